// Round 1
// baseline (542.611 us; speedup 1.0000x reference)
//
#include <hip/hip_runtime.h>

#define PI_D 3.141592653589793238462643383279502884

// Shapes: x (8,256,256,64) f32; weights (16,16,16) f32; out (8,256,256,64) f32.
// Forward padded FFT sizes: (272,272,80), pad=8. Inverse sizes: (256,256,64).
// x_ft = Re(F) - Im(F); out = Re(G) - Im(G), G = IFFT(xwb real).

// ---------------- twiddle tables (double-precision build) ----------------
__global__ void k_tables(float2* __restrict__ wt, float2* __restrict__ wxy,
                         float2* __restrict__ vt, float2* __restrict__ vxy) {
  int t = blockIdx.x * blockDim.x + threadIdx.x;
  if (t < 64 * 16) {  // wt[n3][k3] = exp(-2pi i k3 (n3+8)/80)
    int n3 = t >> 4, k3 = t & 15;
    int ph = (k3 * (n3 + 8)) % 80;
    double a = -2.0 * PI_D * (double)ph / 80.0;
    wt[t] = make_float2((float)cos(a), (float)sin(a));
  }
  if (t < 256 * 32) {  // wxy[n][k] = exp(-2pi i kk (n+8)/272), kk = k<16 ? k : 240+k
    int n = t >> 5, k = t & 31;
    int kk = (k < 16) ? k : (240 + k);
    int ph = (kk * (n + 8)) % 272;
    double a = -2.0 * PI_D * (double)ph / 272.0;
    wxy[t] = make_float2((float)cos(a), (float)sin(a));
  }
  if (t < 16 * 64) {  // vt[k3][n3] = exp(+2pi i k3 n3 / 64)
    int k3 = t >> 6, n3 = t & 63;
    int ph = (k3 * n3) & 63;
    double a = 2.0 * PI_D * (double)ph / 64.0;
    vt[t] = make_float2((float)cos(a), (float)sin(a));
  }
  if (t < 256 * 32) {  // vxy[n][k] = exp(+2pi i k n / 256)
    int n = t >> 5, k = t & 31;
    int ph = (k * n) & 255;
    double a = 2.0 * PI_D * (double)ph / 256.0;
    vxy[t] = make_float2((float)cos(a), (float)sin(a));
  }
}

// ---------------- Step A: T-axis forward DFT ----------------
// A[b,n1,n2,k3] = sum_n3 x[b,n1,n2,n3] * wt[n3][k3]   (k3 in [0,16))
__global__ __launch_bounds__(256) void k_fft_t(const float* __restrict__ x,
                                               float2* __restrict__ A,
                                               const float2* __restrict__ wt) {
  long row = (long)blockIdx.x * 256 + threadIdx.x;  // (b,n1,n2), 524288 rows
  const float4* xr = (const float4*)(x + row * 64);
  float2 acc[16];
#pragma unroll
  for (int k = 0; k < 16; k++) acc[k] = make_float2(0.f, 0.f);
#pragma unroll 4
  for (int i = 0; i < 16; i++) {
    float4 v = xr[i];
    const float2* wr = wt + i * 64;  // rows n3 = 4i .. 4i+3 (uniform -> s_load)
#pragma unroll
    for (int k = 0; k < 16; k++) {
      float2 w0 = wr[k];
      acc[k].x = fmaf(v.x, w0.x, acc[k].x);
      acc[k].y = fmaf(v.x, w0.y, acc[k].y);
      float2 w1 = wr[16 + k];
      acc[k].x = fmaf(v.y, w1.x, acc[k].x);
      acc[k].y = fmaf(v.y, w1.y, acc[k].y);
      float2 w2 = wr[32 + k];
      acc[k].x = fmaf(v.z, w2.x, acc[k].x);
      acc[k].y = fmaf(v.z, w2.y, acc[k].y);
      float2 w3 = wr[48 + k];
      acc[k].x = fmaf(v.w, w3.x, acc[k].x);
      acc[k].y = fmaf(v.w, w3.y, acc[k].y);
    }
  }
  float4* Ao = (float4*)(A + row * 16);
#pragma unroll
  for (int k = 0; k < 8; k++)
    Ao[k] = make_float4(acc[2 * k].x, acc[2 * k].y, acc[2 * k + 1].x, acc[2 * k + 1].y);
}

// ---------------- Step B: Y-axis forward DFT ----------------
// Bm[b,n1,k2,k3] = sum_n2 A[b,n1,n2,k3] * wxy[n2][k2]   (k2 in [0,32))
__global__ __launch_bounds__(512) void k_fft_y(const float2* __restrict__ A,
                                               float2* __restrict__ Bm,
                                               const float2* __restrict__ wxy) {
  __shared__ float2 sA[4096];  // 32 KB: [n2][k3]
  int bn1 = blockIdx.x;        // b*256 + n1
  const float2* Ar = A + (long)bn1 * 4096;
  for (int i = threadIdx.x; i < 4096; i += 512) sA[i] = Ar[i];
  __syncthreads();
  int k2 = threadIdx.x >> 4, k3 = threadIdx.x & 15;
  float2 acc = make_float2(0.f, 0.f);
#pragma unroll 8
  for (int n2 = 0; n2 < 256; n2++) {
    float2 a = sA[n2 * 16 + k3];
    float2 w = wxy[n2 * 32 + k2];
    acc.x = fmaf(a.x, w.x, fmaf(-a.y, w.y, acc.x));
    acc.y = fmaf(a.x, w.y, fmaf(a.y, w.x, acc.y));
  }
  Bm[(long)bn1 * 512 + threadIdx.x] = acc;
}

// ---------------- Step C: X-axis forward DFT + weight multiply ----------------
// y[b,k1,k2,k3] = (Re-Im)(sum_n1 Bm[b,n1,k2,k3]*wxy[n1][k1]) * w_sel + b_sel
__global__ __launch_bounds__(512) void k_fft_x(
    const float2* __restrict__ Bm, float* __restrict__ y,
    const float2* __restrict__ wxy,
    const float* __restrict__ w_tl, const float* __restrict__ w_tr,
    const float* __restrict__ w_bl, const float* __restrict__ w_br,
    const float* __restrict__ b_tl, const float* __restrict__ b_tr,
    const float* __restrict__ b_bl, const float* __restrict__ b_br) {
  __shared__ float2 sB[4096];  // [n1][k3]
  int b = blockIdx.x >> 5, k2 = blockIdx.x & 31;
  for (int i = threadIdx.x; i < 4096; i += 512) {
    int n1 = i >> 4, k3 = i & 15;
    sB[i] = Bm[((long)(b * 256 + n1) * 32 + k2) * 16 + k3];
  }
  __syncthreads();
  int k1 = threadIdx.x >> 4, k3 = threadIdx.x & 15;
  float2 acc = make_float2(0.f, 0.f);
#pragma unroll 8
  for (int n1 = 0; n1 < 256; n1++) {
    float2 a = sB[n1 * 16 + k3];
    float2 w = wxy[n1 * 32 + k1];
    acc.x = fmaf(a.x, w.x, fmaf(-a.y, w.y, acc.x));
    acc.y = fmaf(a.x, w.y, fmaf(a.y, w.x, acc.y));
  }
  float xft = acc.x - acc.y;
  const float* wsel = (k1 < 16) ? ((k2 < 16) ? w_tl : w_bl) : ((k2 < 16) ? w_tr : w_br);
  const float* bsel = (k1 < 16) ? ((k2 < 16) ? b_tl : b_bl) : ((k2 < 16) ? b_tr : b_br);
  int idx = ((k1 & 15) * 16 + (k2 & 15)) * 16 + k3;
  y[((b * 32 + k1) * 32 + k2) * 16 + k3] = fmaf(xft, wsel[idx], bsel[idx]);
}

// ---------------- Step D: T-axis inverse DFT ----------------
// D[b,k1,k2,n3] = sum_k3 y[b,k1,k2,k3] * vt[k3][n3]
__global__ __launch_bounds__(256) void k_ifft_t(const float* __restrict__ y,
                                                float2* __restrict__ D,
                                                const float2* __restrict__ vt) {
  int t = blockIdx.x * 256 + threadIdx.x;  // 524288
  int n3 = t & 63, g = t >> 6;             // g = (b,k1,k2)
  const float* yr = y + g * 16;            // wave-uniform -> s_load
  float2 acc = make_float2(0.f, 0.f);
#pragma unroll
  for (int k3 = 0; k3 < 16; k3++) {
    float yv = yr[k3];
    float2 v = vt[k3 * 64 + n3];
    acc.x = fmaf(yv, v.x, acc.x);
    acc.y = fmaf(yv, v.y, acc.y);
  }
  D[t] = acc;
}

// ---------------- Step E: Y-axis inverse DFT ----------------
// E[b,k1,n2,n3] = sum_k2 D[b,k1,k2,n3] * vxy[n2][k2]
__global__ __launch_bounds__(256) void k_ifft_y(const float2* __restrict__ D,
                                                float2* __restrict__ E,
                                                const float2* __restrict__ vxy) {
  __shared__ float2 sD[2048];  // [k2][n3], 16 KB
  int bk1 = blockIdx.x;        // b*32 + k1
  for (int i = threadIdx.x; i < 2048; i += 256) sD[i] = D[(long)bk1 * 2048 + i];
  __syncthreads();
  int n3 = threadIdx.x & 63, wv = threadIdx.x >> 6;
  float2 d[32];
#pragma unroll
  for (int k2 = 0; k2 < 32; k2++) d[k2] = sD[k2 * 64 + n3];
  for (int n2 = wv; n2 < 256; n2 += 4) {
    float2 acc = make_float2(0.f, 0.f);
    const float2* vr = vxy + n2 * 32;  // wave-uniform rows -> s_load
    float2 a;
#pragma unroll
    for (int k2 = 0; k2 < 32; k2++) {
      float2 v = vr[k2];
      a = d[k2];
      acc.x = fmaf(a.x, v.x, fmaf(-a.y, v.y, acc.x));
      acc.y = fmaf(a.x, v.y, fmaf(a.y, v.x, acc.y));
    }
    E[((long)bk1 * 256 + n2) * 64 + n3] = acc;
  }
}

// ---------------- Step F: X-axis inverse DFT + Re-Im + 1/N ----------------
// out[b,n1,n2,n3] = (Re-Im)(sum_k1 E[b,k1,n2,n3]*vxy[n1][k1]) / (256*256*64)
__global__ __launch_bounds__(256) void k_ifft_x(const float2* __restrict__ E,
                                                float* __restrict__ out,
                                                const float2* __restrict__ vxy) {
  __shared__ float2 sE[2048];  // [k1][n3], 16 KB
  int b = blockIdx.x >> 8, n2 = blockIdx.x & 255;
  for (int i = threadIdx.x; i < 2048; i += 256) {
    int k1 = i >> 6, n3 = i & 63;
    sE[i] = E[((long)(b * 32 + k1) * 256 + n2) * 64 + n3];
  }
  __syncthreads();
  int n3 = threadIdx.x & 63, wv = threadIdx.x >> 6;
  float2 e[32];
#pragma unroll
  for (int k1 = 0; k1 < 32; k1++) e[k1] = sE[k1 * 64 + n3];
  const float invN = 1.0f / (256.0f * 256.0f * 64.0f);
  for (int n1 = wv; n1 < 256; n1 += 4) {
    float2 acc = make_float2(0.f, 0.f);
    const float2* vr = vxy + n1 * 32;  // wave-uniform -> s_load
    float2 a;
#pragma unroll
    for (int k1 = 0; k1 < 32; k1++) {
      float2 v = vr[k1];
      a = e[k1];
      acc.x = fmaf(a.x, v.x, fmaf(-a.y, v.y, acc.x));
      acc.y = fmaf(a.x, v.y, fmaf(a.y, v.x, acc.y));
    }
    out[((long)(b * 256 + n1) * 256 + n2) * 64 + n3] = (acc.x - acc.y) * invN;
  }
}

extern "C" void kernel_launch(void* const* d_in, const int* in_sizes, int n_in,
                              void* d_out, int out_size, void* d_ws, size_t ws_size,
                              hipStream_t stream) {
  const float* x    = (const float*)d_in[0];
  const float* w_tl = (const float*)d_in[1];
  const float* w_tr = (const float*)d_in[2];
  const float* w_bl = (const float*)d_in[3];
  const float* w_br = (const float*)d_in[4];
  const float* b_tl = (const float*)d_in[5];
  const float* b_tr = (const float*)d_in[6];
  const float* b_bl = (const float*)d_in[7];
  const float* b_br = (const float*)d_in[8];
  float* out = (float*)d_out;
  char* ws = (char*)d_ws;

  // Workspace layout (bytes):
  float2* Bm  = (float2*)(ws + 0);          //  8,388,608  (8,256,32,16) c64
  float*  y   = (float*)(ws + 8388608);     //  2,097,152  (8,32,32,16)  f32
  float2* D   = (float2*)(ws + 10485760);   //  4,194,304  (8,32,32,64)  c64
  float2* E   = (float2*)(ws + 14680064);   // 33,554,432  (8,32,256,64) c64
  float2* WT  = (float2*)(ws + 48234496);   //  8 KB
  float2* WXY = (float2*)(ws + 48242688);   // 64 KB
  float2* VT  = (float2*)(ws + 48308224);   //  8 KB
  float2* VXY = (float2*)(ws + 48316416);   // 64 KB
  // Stage-A output (67 MB) aliases d_out; it is fully dead before k_ifft_x writes out.
  float2* A = (float2*)d_out;

  k_tables<<<32, 256, 0, stream>>>(WT, WXY, VT, VXY);
  k_fft_t<<<2048, 256, 0, stream>>>(x, A, WT);
  k_fft_y<<<2048, 512, 0, stream>>>(A, Bm, WXY);
  k_fft_x<<<256, 512, 0, stream>>>(Bm, y, WXY, w_tl, w_tr, w_bl, w_br,
                                   b_tl, b_tr, b_bl, b_br);
  k_ifft_t<<<2048, 256, 0, stream>>>(y, D, VT);
  k_ifft_y<<<256, 256, 0, stream>>>(D, E, VXY);
  k_ifft_x<<<2048, 256, 0, stream>>>(E, out, VXY);
}

// Round 2
// 296.654 us; speedup vs baseline: 1.8291x; 1.8291x over previous
//
#include <hip/hip_runtime.h>

#define PI_D 3.141592653589793238462643383279502884

// x (8,256,256,64) f32 -> out (8,256,256,64) f32.
// Forward padded FFT (272,272,80) pad=8; x_ft = Re(F)-Im(F) on 4 corner blocks.
// Inverse (256,256,64); out = Re(G)-Im(G).
// Re-Im collapse: Re-Im(sum a*w) = sum a.x*(w.x-w.y) + a.y*(-(w.x+w.y)) = sum a.x*P + a.y*Qm.

// ---------------- twiddle tables (double-precision build) ----------------
__global__ void k_tables(float2* __restrict__ wt, float2* __restrict__ wxy,
                         float2* __restrict__ vt, float2* __restrict__ vxy,
                         float2* __restrict__ pqf, float2* __restrict__ pqi) {
  int t = blockIdx.x * blockDim.x + threadIdx.x;
  if (t < 64 * 16) {  // wt[n3][k3] = exp(-2pi i k3 (n3+8)/80)
    int n3 = t >> 4, k3 = t & 15;
    int ph = (k3 * (n3 + 8)) % 80;
    double a = -2.0 * PI_D * (double)ph / 80.0;
    wt[t] = make_float2((float)cos(a), (float)sin(a));
  }
  if (t < 256 * 32) {  // wxy[n][k] = exp(-2pi i kk (n+8)/272), kk = k<16 ? k : 240+k
    int n = t >> 5, k = t & 31;
    int kk = (k < 16) ? k : (240 + k);
    int ph = (kk * (n + 8)) % 272;
    double a = -2.0 * PI_D * (double)ph / 272.0;
    double c = cos(a), s = sin(a);
    wxy[t] = make_float2((float)c, (float)s);
    pqf[t] = make_float2((float)(c - s), (float)(-(c + s)));  // P, Qm (forward)
  }
  if (t < 16 * 64) {  // vt[k3][n3] = exp(+2pi i k3 n3 / 64)
    int k3 = t >> 6, n3 = t & 63;
    int ph = (k3 * n3) & 63;
    double a = 2.0 * PI_D * (double)ph / 64.0;
    vt[t] = make_float2((float)cos(a), (float)sin(a));
  }
  if (t < 256 * 32) {  // vxy[n][k] = exp(+2pi i k n / 256)
    int n = t >> 5, k = t & 31;
    int ph = (k * n) & 255;
    double a = 2.0 * PI_D * (double)ph / 256.0;
    double c = cos(a), s = sin(a);
    vxy[t] = make_float2((float)c, (float)s);
    pqi[t] = make_float2((float)(c - s), (float)(-(c + s)));  // P, Qm (inverse)
  }
}

// ---------------- Step A: T-axis forward DFT (LDS-transposed, coalesced) ----------------
// A[b,n1,n2,k3] = sum_n3 x[b,n1,n2,n3] * wt[n3][k3]
__global__ __launch_bounds__(256) void k_fft_t(const float* __restrict__ x,
                                               float2* __restrict__ A,
                                               const float2* __restrict__ wt) {
  __shared__ float sX[64][65];   // 64 rows x 64 cols, +1 pad
  __shared__ float2 swt[1024];   // wt[64][16]
  long blk = blockIdx.x;         // 8192 blocks x 64 rows
  int tid = threadIdx.x;
  const float4* xg = (const float4*)(x + blk * 4096);
#pragma unroll
  for (int e = 0; e < 4; e++) {
    int idx = tid + e * 256;  // 1024 float4, fully coalesced
    float4 v = xg[idx];
    int r = idx >> 4, c = (idx & 15) * 4;
    sX[r][c] = v.x; sX[r][c + 1] = v.y; sX[r][c + 2] = v.z; sX[r][c + 3] = v.w;
  }
#pragma unroll
  for (int e = 0; e < 4; e++) swt[tid + e * 256] = wt[tid + e * 256];
  __syncthreads();
  int r = tid >> 2, q = (tid & 3) * 4;  // row, k-quad
  float2 a0 = {0,0}, a1 = {0,0}, a2 = {0,0}, a3 = {0,0};
#pragma unroll 8
  for (int n3 = 0; n3 < 64; n3++) {
    float xv = sX[r][n3];
    const float2* wr = &swt[n3 * 16 + q];
    float2 w0 = wr[0], w1 = wr[1], w2 = wr[2], w3 = wr[3];
    a0.x = fmaf(xv, w0.x, a0.x); a0.y = fmaf(xv, w0.y, a0.y);
    a1.x = fmaf(xv, w1.x, a1.x); a1.y = fmaf(xv, w1.y, a1.y);
    a2.x = fmaf(xv, w2.x, a2.x); a2.y = fmaf(xv, w2.y, a2.y);
    a3.x = fmaf(xv, w3.x, a3.x); a3.y = fmaf(xv, w3.y, a3.y);
  }
  float4* Ao = (float4*)(A + (blk * 64 + r) * 16 + q);
  Ao[0] = make_float4(a0.x, a0.y, a1.x, a1.y);
  Ao[1] = make_float4(a2.x, a2.y, a3.x, a3.y);
}

// ---------------- Step B: Y-axis forward DFT ----------------
// Bm[b,n1,k2,k3] = sum_n2 A[b,n1,n2,k3] * wxy[n2][k2]
__global__ __launch_bounds__(256) void k_fft_y(const float2* __restrict__ A,
                                               float2* __restrict__ Bm,
                                               const float2* __restrict__ wxy) {
  __shared__ float2 sA[4096];  // [n2][k3] 32 KB
  int bn1 = blockIdx.x;
  int tid = threadIdx.x;
  const float4* Ag = (const float4*)(A + (long)bn1 * 4096);
  float4* sA4 = (float4*)sA;
#pragma unroll
  for (int e = 0; e < 8; e++) sA4[tid + e * 256] = Ag[tid + e * 256];
  __syncthreads();
  int k2 = tid >> 3, p = (tid & 7) * 2;  // two k3 per thread: p, p+1
  float2 r0 = {0,0}, r1 = {0,0};
#pragma unroll 4
  for (int n2 = 0; n2 < 256; n2++) {
    float4 av = *(const float4*)&sA[n2 * 16 + p];
    float2 w = wxy[n2 * 32 + k2];
    r0.x = fmaf(av.x, w.x, r0.x); r0.x = fmaf(-av.y, w.y, r0.x);
    r0.y = fmaf(av.x, w.y, r0.y); r0.y = fmaf(av.y, w.x, r0.y);
    r1.x = fmaf(av.z, w.x, r1.x); r1.x = fmaf(-av.w, w.y, r1.x);
    r1.y = fmaf(av.z, w.y, r1.y); r1.y = fmaf(av.w, w.x, r1.y);
  }
  float4* Bo = (float4*)(Bm + (long)bn1 * 512 + k2 * 16 + p);
  *Bo = make_float4(r0.x, r0.y, r1.x, r1.y);
}

// ---------------- Step C: X-axis forward DFT (Re-Im collapsed) + weights ----------------
__global__ __launch_bounds__(512) void k_fft_x(
    const float2* __restrict__ Bm, float* __restrict__ y,
    const float2* __restrict__ pqf,
    const float* __restrict__ w_tl, const float* __restrict__ w_tr,
    const float* __restrict__ w_bl, const float* __restrict__ w_br,
    const float* __restrict__ b_tl, const float* __restrict__ b_tr,
    const float* __restrict__ b_bl, const float* __restrict__ b_br) {
  __shared__ float2 sB[4096];  // [n1][k3]
  int b = blockIdx.x >> 5, k2 = blockIdx.x & 31;
  for (int i = threadIdx.x; i < 4096; i += 512) {
    sB[i] = Bm[((long)(b * 256 + (i >> 4)) * 32 + k2) * 16 + (i & 15)];
  }
  __syncthreads();
  int k1 = threadIdx.x >> 4, k3 = threadIdx.x & 15;
  float acc = 0.f;
#pragma unroll 8
  for (int n1 = 0; n1 < 256; n1++) {
    float2 a = sB[n1 * 16 + k3];
    float2 w = pqf[n1 * 32 + k1];  // (P, Qm)
    acc = fmaf(a.x, w.x, acc);
    acc = fmaf(a.y, w.y, acc);
  }
  const float* wsel = (k1 < 16) ? ((k2 < 16) ? w_tl : w_bl) : ((k2 < 16) ? w_tr : w_br);
  const float* bsel = (k1 < 16) ? ((k2 < 16) ? b_tl : b_bl) : ((k2 < 16) ? b_tr : b_br);
  int idx = ((k1 & 15) * 16 + (k2 & 15)) * 16 + k3;
  y[((b * 32 + k1) * 32 + k2) * 16 + k3] = fmaf(acc, wsel[idx], bsel[idx]);
}

// ---------------- Steps D+E fused: T-axis then Y-axis inverse DFT ----------------
// D[k2,n3] = sum_k3 y[b,k1,k2,k3]*vt[k3][n3]  (recomputed per block in LDS)
// E[b,k1,n2,n3] = sum_k2 D[k2,n3] * vxy[n2][k2]
__global__ __launch_bounds__(256) void k_inv_te(const float* __restrict__ y,
                                                float2* __restrict__ E,
                                                const float2* __restrict__ vt,
                                                const float2* __restrict__ vxy) {
  __shared__ float sy[512];     // y[b,k1,:,:]  32x16
  __shared__ float2 svt[1024];  // vt[16][64]
  __shared__ float2 sD[2048];   // D[k2][n3]  32x64
  int blk = blockIdx.x;         // (b*32+k1)*8 + c
  int c = blk & 7, bk1 = blk >> 3;
  int tid = threadIdx.x;
  ((float2*)sy)[tid] = ((const float2*)(y + (long)bk1 * 512))[tid];
#pragma unroll
  for (int e = 0; e < 4; e++) svt[tid + e * 256] = vt[tid + e * 256];
  __syncthreads();
#pragma unroll
  for (int e = 0; e < 8; e++) {
    int idx = tid + e * 256;
    int k2 = idx >> 6, n3i = idx & 63;
    float ax = 0.f, ay = 0.f;
#pragma unroll
    for (int k3 = 0; k3 < 16; k3++) {
      float yv = sy[k2 * 16 + k3];
      float2 v = svt[k3 * 64 + n3i];
      ax = fmaf(yv, v.x, ax); ay = fmaf(yv, v.y, ay);
    }
    sD[idx] = make_float2(ax, ay);
  }
  __syncthreads();
  int n3 = tid & 63;
  int wvu = __builtin_amdgcn_readfirstlane(tid >> 6);
  float dx[32], dy[32];
#pragma unroll
  for (int k2 = 0; k2 < 32; k2++) { float2 t = sD[k2 * 64 + n3]; dx[k2] = t.x; dy[k2] = t.y; }
  int n2base = c * 32 + wvu * 8;
  for (int i = 0; i < 8; i += 2) {
    int n2a = n2base + i;
    const float2* va = vxy + n2a * 32;
    const float2* vb = va + 32;
    float arx = 0.f, ary = 0.f, brx = 0.f, bry = 0.f;
#pragma unroll 8
    for (int k2 = 0; k2 < 32; k2++) {
      float2 w = va[k2];
      arx = fmaf(dx[k2], w.x, arx); arx = fmaf(-dy[k2], w.y, arx);
      ary = fmaf(dx[k2], w.y, ary); ary = fmaf(dy[k2], w.x, ary);
      float2 u = vb[k2];
      brx = fmaf(dx[k2], u.x, brx); brx = fmaf(-dy[k2], u.y, brx);
      bry = fmaf(dx[k2], u.y, bry); bry = fmaf(dy[k2], u.x, bry);
    }
    E[((long)bk1 * 256 + n2a) * 64 + n3] = make_float2(arx, ary);
    E[((long)bk1 * 256 + n2a + 1) * 64 + n3] = make_float2(brx, bry);
  }
}

// ---------------- Step F: X-axis inverse DFT (Re-Im collapsed) ----------------
// out[b,n1,n2,n3] = (1/N) * sum_k1 (E.x*P + E.y*Qm),  (P,Qm) = pqi[n1][k1]
__global__ __launch_bounds__(256) void k_ifft_x(const float2* __restrict__ E,
                                                float* __restrict__ out,
                                                const float2* __restrict__ pqi) {
  __shared__ float2 sE[2048];  // [k1][n3] 16 KB
  int b = blockIdx.x >> 8, n2 = blockIdx.x & 255;
  int tid = threadIdx.x;
  const float4* Eg = (const float4*)E;
  float4* sE4 = (float4*)sE;
#pragma unroll
  for (int e = 0; e < 4; e++) {
    int i = tid + e * 256;  // 1024 float4
    int k1 = i >> 5, col = i & 31;
    sE4[i] = Eg[((long)(b * 32 + k1) * 256 + n2) * 32 + col];
  }
  __syncthreads();
  int n3 = tid & 63;
  int wvu = __builtin_amdgcn_readfirstlane(tid >> 6);
  float ex[32], ey[32];
#pragma unroll
  for (int k1 = 0; k1 < 32; k1++) { float2 t = sE[k1 * 64 + n3]; ex[k1] = t.x; ey[k1] = t.y; }
  const float invN = 1.0f / (256.0f * 256.0f * 64.0f);
  float* ob = out + (long)b * 4194304 + n2 * 64 + n3;  // + n1*16384
  for (int j = 0; j < 64; j += 4) {
    int n1 = wvu * 64 + j;
    const float2* p0 = pqi + n1 * 32;
    const float2* p1 = p0 + 32;
    const float2* p2 = p0 + 64;
    const float2* p3 = p0 + 96;
    float a0 = 0.f, a1 = 0.f, a2 = 0.f, a3 = 0.f;
#pragma unroll 8
    for (int k1 = 0; k1 < 32; k1++) {
      float exk = ex[k1], eyk = ey[k1];
      float2 w0 = p0[k1]; a0 = fmaf(exk, w0.x, a0); a0 = fmaf(eyk, w0.y, a0);
      float2 w1 = p1[k1]; a1 = fmaf(exk, w1.x, a1); a1 = fmaf(eyk, w1.y, a1);
      float2 w2 = p2[k1]; a2 = fmaf(exk, w2.x, a2); a2 = fmaf(eyk, w2.y, a2);
      float2 w3 = p3[k1]; a3 = fmaf(exk, w3.x, a3); a3 = fmaf(eyk, w3.y, a3);
    }
    ob[(long)(n1 + 0) * 16384] = a0 * invN;
    ob[(long)(n1 + 1) * 16384] = a1 * invN;
    ob[(long)(n1 + 2) * 16384] = a2 * invN;
    ob[(long)(n1 + 3) * 16384] = a3 * invN;
  }
}

extern "C" void kernel_launch(void* const* d_in, const int* in_sizes, int n_in,
                              void* d_out, int out_size, void* d_ws, size_t ws_size,
                              hipStream_t stream) {
  const float* x    = (const float*)d_in[0];
  const float* w_tl = (const float*)d_in[1];
  const float* w_tr = (const float*)d_in[2];
  const float* w_bl = (const float*)d_in[3];
  const float* w_br = (const float*)d_in[4];
  const float* b_tl = (const float*)d_in[5];
  const float* b_tr = (const float*)d_in[6];
  const float* b_bl = (const float*)d_in[7];
  const float* b_br = (const float*)d_in[8];
  float* out = (float*)d_out;
  char* ws = (char*)d_ws;

  // Workspace layout (bytes):
  float2* Bm  = (float2*)(ws + 0);          //  8,388,608  (8,256,32,16) c64
  float*  y   = (float*)(ws + 8388608);     //  2,097,152  (8,32,32,16)  f32
  float2* E   = (float2*)(ws + 10485760);   // 33,554,432  (8,32,256,64) c64
  float2* WT  = (float2*)(ws + 44040192);   //  8 KB
  float2* WXY = (float2*)(ws + 44048384);   // 64 KB
  float2* VT  = (float2*)(ws + 44113920);   //  8 KB
  float2* VXY = (float2*)(ws + 44122112);   // 64 KB
  float2* PQF = (float2*)(ws + 44187648);   // 64 KB
  float2* PQI = (float2*)(ws + 44253184);   // 64 KB  (end ~44.3 MB)
  // Stage-A output (67 MB) aliases d_out; dead before k_ifft_x writes out.
  float2* A = (float2*)d_out;

  k_tables<<<32, 256, 0, stream>>>(WT, WXY, VT, VXY, PQF, PQI);
  k_fft_t<<<8192, 256, 0, stream>>>(x, A, WT);
  k_fft_y<<<2048, 256, 0, stream>>>(A, Bm, WXY);
  k_fft_x<<<256, 512, 0, stream>>>(Bm, y, PQF, w_tl, w_tr, w_bl, w_br,
                                   b_tl, b_tr, b_bl, b_br);
  k_inv_te<<<2048, 256, 0, stream>>>(y, E, VT, VXY);
  k_ifft_x<<<2048, 256, 0, stream>>>(E, out, PQI);
}

// Round 3
// 276.340 us; speedup vs baseline: 1.9636x; 1.0735x over previous
//
#include <hip/hip_runtime.h>

#define PI_D 3.141592653589793238462643383279502884

// x (8,256,256,64) f32 -> out (8,256,256,64) f32.
// Forward padded FFT (272,272,80) pad=8; x_ft = Re(F)-Im(F) on 4 corner blocks.
// Inverse (256,256,64); out = Re(G)-Im(G).
// Re-Im collapse: Re-Im(sum a*w) = sum a.x*(w.x-w.y) + a.y*(-(w.x+w.y)) = sum a.x*P + a.y*Qm.

// ---------------- twiddle tables (double-precision build) ----------------
__global__ void k_tables(float2* __restrict__ wt, float2* __restrict__ wxy,
                         float2* __restrict__ vt, float2* __restrict__ vxy,
                         float2* __restrict__ pqf, float2* __restrict__ pqi) {
  int t = blockIdx.x * blockDim.x + threadIdx.x;
  if (t < 64 * 16) {  // wt[n3][k3] = exp(-2pi i k3 (n3+8)/80)
    int n3 = t >> 4, k3 = t & 15;
    int ph = (k3 * (n3 + 8)) % 80;
    double a = -2.0 * PI_D * (double)ph / 80.0;
    wt[t] = make_float2((float)cos(a), (float)sin(a));
  }
  if (t < 256 * 32) {  // wxy[n][k] = exp(-2pi i kk (n+8)/272), kk = k<16 ? k : 240+k
    int n = t >> 5, k = t & 31;
    int kk = (k < 16) ? k : (240 + k);
    int ph = (kk * (n + 8)) % 272;
    double a = -2.0 * PI_D * (double)ph / 272.0;
    double c = cos(a), s = sin(a);
    wxy[t] = make_float2((float)c, (float)s);
    pqf[t] = make_float2((float)(c - s), (float)(-(c + s)));  // P, Qm (forward)
  }
  if (t < 16 * 64) {  // vt[k3][n3] = exp(+2pi i k3 n3 / 64)
    int k3 = t >> 6, n3 = t & 63;
    int ph = (k3 * n3) & 63;
    double a = 2.0 * PI_D * (double)ph / 64.0;
    vt[t] = make_float2((float)cos(a), (float)sin(a));
  }
  if (t < 256 * 32) {  // vxy[n][k] = exp(+2pi i k n / 256)
    int n = t >> 5, k = t & 31;
    int ph = (k * n) & 255;
    double a = 2.0 * PI_D * (double)ph / 256.0;
    double c = cos(a), s = sin(a);
    vxy[t] = make_float2((float)c, (float)s);
    pqi[t] = make_float2((float)(c - s), (float)(-(c + s)));  // P, Qm (inverse)
  }
}

// ---------------- Step A: T-axis forward DFT (LDS-transposed, coalesced) ----------------
// A[b,n1,n2,k3] = sum_n3 x[b,n1,n2,n3] * wt[n3][k3]
__global__ __launch_bounds__(256) void k_fft_t(const float* __restrict__ x,
                                               float2* __restrict__ A,
                                               const float2* __restrict__ wt) {
  __shared__ float sX[64][65];   // 64 rows x 64 cols, +1 pad
  __shared__ float2 swt[1024];   // wt[64][16]
  long blk = blockIdx.x;         // 8192 blocks x 64 rows
  int tid = threadIdx.x;
  const float4* xg = (const float4*)(x + blk * 4096);
#pragma unroll
  for (int e = 0; e < 4; e++) {
    int idx = tid + e * 256;  // 1024 float4, fully coalesced
    float4 v = xg[idx];
    int r = idx >> 4, c = (idx & 15) * 4;
    sX[r][c] = v.x; sX[r][c + 1] = v.y; sX[r][c + 2] = v.z; sX[r][c + 3] = v.w;
  }
#pragma unroll
  for (int e = 0; e < 4; e++) swt[tid + e * 256] = wt[tid + e * 256];
  __syncthreads();
  int r = tid >> 2, q = (tid & 3) * 4;  // row, k-quad
  float2 a0 = {0,0}, a1 = {0,0}, a2 = {0,0}, a3 = {0,0};
#pragma unroll 8
  for (int n3 = 0; n3 < 64; n3++) {
    float xv = sX[r][n3];
    const float2* wr = &swt[n3 * 16 + q];
    float2 w0 = wr[0], w1 = wr[1], w2 = wr[2], w3 = wr[3];
    a0.x = fmaf(xv, w0.x, a0.x); a0.y = fmaf(xv, w0.y, a0.y);
    a1.x = fmaf(xv, w1.x, a1.x); a1.y = fmaf(xv, w1.y, a1.y);
    a2.x = fmaf(xv, w2.x, a2.x); a2.y = fmaf(xv, w2.y, a2.y);
    a3.x = fmaf(xv, w3.x, a3.x); a3.y = fmaf(xv, w3.y, a3.y);
  }
  float4* Ao = (float4*)(A + (blk * 64 + r) * 16 + q);
  Ao[0] = make_float4(a0.x, a0.y, a1.x, a1.y);
  Ao[1] = make_float4(a2.x, a2.y, a3.x, a3.y);
}

// ---------------- Step B: Y-axis forward DFT (LDS-chunked twiddles) ----------------
// Bm[b,n1,k2,k3] = sum_n2 A[b,n1,n2,k3] * wxy[n2][k2]
__global__ __launch_bounds__(256) void k_fft_y(const float2* __restrict__ A,
                                               float2* __restrict__ Bm,
                                               const float2* __restrict__ wxy) {
  __shared__ float2 sA[4096];  // [n2][k3] 32 KB
  __shared__ float2 sW[2048];  // [64 n2][32 k2] chunk, 16 KB
  int bn1 = blockIdx.x;
  int tid = threadIdx.x;
  const float4* Ag = (const float4*)(A + (long)bn1 * 4096);
  float4* sA4 = (float4*)sA;
#pragma unroll
  for (int e = 0; e < 8; e++) sA4[tid + e * 256] = Ag[tid + e * 256];
  int k2 = tid >> 3, p = (tid & 7) * 2;  // two k3 per thread: p, p+1
  float2 r0 = {0,0}, r1 = {0,0};
  const float4* wg4 = (const float4*)wxy;
  float4* sW4 = (float4*)sW;
  for (int ch = 0; ch < 4; ch++) {
    __syncthreads();  // also covers the sA staging before ch 0
#pragma unroll
    for (int e = 0; e < 4; e++) sW4[tid + e * 256] = wg4[ch * 1024 + tid + e * 256];
    __syncthreads();
#pragma unroll 4
    for (int t = 0; t < 64; t++) {
      float4 av = *(const float4*)&sA[(ch * 64 + t) * 16 + p];
      float2 w = sW[t * 32 + k2];
      r0.x = fmaf(av.x, w.x, r0.x); r0.x = fmaf(-av.y, w.y, r0.x);
      r0.y = fmaf(av.x, w.y, r0.y); r0.y = fmaf(av.y, w.x, r0.y);
      r1.x = fmaf(av.z, w.x, r1.x); r1.x = fmaf(-av.w, w.y, r1.x);
      r1.y = fmaf(av.z, w.y, r1.y); r1.y = fmaf(av.w, w.x, r1.y);
    }
  }
  float4* Bo = (float4*)(Bm + (long)bn1 * 512 + k2 * 16 + p);
  *Bo = make_float4(r0.x, r0.y, r1.x, r1.y);
}

// ---------------- Step C: X-axis forward DFT (all-LDS, Re-Im collapsed) ----------------
__global__ __launch_bounds__(512) void k_fft_x(
    const float2* __restrict__ Bm, float* __restrict__ y,
    const float2* __restrict__ pqf,
    const float* __restrict__ w_tl, const float* __restrict__ w_tr,
    const float* __restrict__ w_bl, const float* __restrict__ w_br,
    const float* __restrict__ b_tl, const float* __restrict__ b_tr,
    const float* __restrict__ b_bl, const float* __restrict__ b_br) {
  __shared__ float2 sB[4096];   // [n1][k3] 32 KB
  __shared__ float2 sPQ[8192];  // full pqf table, 64 KB  (96 KB total, 1 block/CU)
  int b = blockIdx.x >> 5, k2 = blockIdx.x & 31;
  int tid = threadIdx.x;
  for (int i = tid; i < 4096; i += 512) {
    sB[i] = Bm[((long)(b * 256 + (i >> 4)) * 32 + k2) * 16 + (i & 15)];
  }
  const float4* pq4 = (const float4*)pqf;
  float4* sPQ4 = (float4*)sPQ;
#pragma unroll
  for (int e = 0; e < 8; e++) sPQ4[tid + e * 512] = pq4[tid + e * 512];
  __syncthreads();
  int k1 = tid >> 4, k3 = tid & 15;
  float acc = 0.f;
#pragma unroll 8
  for (int n1 = 0; n1 < 256; n1++) {
    float2 a = sB[n1 * 16 + k3];
    float2 w = sPQ[n1 * 32 + k1];  // (P, Qm)
    acc = fmaf(a.x, w.x, acc);
    acc = fmaf(a.y, w.y, acc);
  }
  const float* wsel = (k1 < 16) ? ((k2 < 16) ? w_tl : w_bl) : ((k2 < 16) ? w_tr : w_br);
  const float* bsel = (k1 < 16) ? ((k2 < 16) ? b_tl : b_bl) : ((k2 < 16) ? b_tr : b_br);
  int idx = ((k1 & 15) * 16 + (k2 & 15)) * 16 + k3;
  y[((b * 32 + k1) * 32 + k2) * 16 + k3] = fmaf(acc, wsel[idx], bsel[idx]);
}

// ---------------- Steps D+E fused: T-axis then Y-axis inverse DFT ----------------
// D[k2,n3] = sum_k3 y[b,k1,k2,k3]*vt[k3][n3]  (recomputed per block in LDS)
// E[b,k1,n2,n3] = sum_k2 D[k2,n3] * vxy[n2][k2]
__global__ __launch_bounds__(256) void k_inv_te(const float* __restrict__ y,
                                                float2* __restrict__ E,
                                                const float2* __restrict__ vt,
                                                const float2* __restrict__ vxy) {
  __shared__ float sy[512];     // y[b,k1,:,:]  32x16
  __shared__ float2 svt[1024];  // vt[16][64]
  __shared__ float2 sD[2048];   // D[k2][n3]  32x64
  __shared__ float2 sV[1024];   // vxy rows c*32 .. c*32+31, 8 KB
  int blk = blockIdx.x;         // (b*32+k1)*8 + c
  int c = blk & 7, bk1 = blk >> 3;
  int tid = threadIdx.x;
  ((float2*)sy)[tid] = ((const float2*)(y + (long)bk1 * 512))[tid];
#pragma unroll
  for (int e = 0; e < 4; e++) svt[tid + e * 256] = vt[tid + e * 256];
#pragma unroll
  for (int e = 0; e < 4; e++) sV[tid + e * 256] = vxy[c * 1024 + tid + e * 256];
  __syncthreads();
#pragma unroll
  for (int e = 0; e < 8; e++) {
    int idx = tid + e * 256;
    int k2 = idx >> 6, n3i = idx & 63;
    float ax = 0.f, ay = 0.f;
#pragma unroll
    for (int k3 = 0; k3 < 16; k3++) {
      float yv = sy[k2 * 16 + k3];
      float2 v = svt[k3 * 64 + n3i];
      ax = fmaf(yv, v.x, ax); ay = fmaf(yv, v.y, ay);
    }
    sD[idx] = make_float2(ax, ay);
  }
  __syncthreads();
  int n3 = tid & 63, wv = tid >> 6;
  float dx[32], dy[32];
#pragma unroll
  for (int k2 = 0; k2 < 32; k2++) { float2 t = sD[k2 * 64 + n3]; dx[k2] = t.x; dy[k2] = t.y; }
  for (int i = 0; i < 8; i += 2) {
    int l2 = wv * 8 + i;               // local n2 row in sV
    const float2* va = &sV[l2 * 32];   // broadcast reads
    const float2* vb = va + 32;
    float arx = 0.f, ary = 0.f, brx = 0.f, bry = 0.f;
#pragma unroll 8
    for (int k2 = 0; k2 < 32; k2++) {
      float2 w = va[k2];
      arx = fmaf(dx[k2], w.x, arx); arx = fmaf(-dy[k2], w.y, arx);
      ary = fmaf(dx[k2], w.y, ary); ary = fmaf(dy[k2], w.x, ary);
      float2 u = vb[k2];
      brx = fmaf(dx[k2], u.x, brx); brx = fmaf(-dy[k2], u.y, brx);
      bry = fmaf(dx[k2], u.y, bry); bry = fmaf(dy[k2], u.x, bry);
    }
    int n2a = c * 32 + l2;
    E[((long)bk1 * 256 + n2a) * 64 + n3] = make_float2(arx, ary);
    E[((long)bk1 * 256 + n2a + 1) * 64 + n3] = make_float2(brx, bry);
  }
}

// ---------------- Step F: X-axis inverse DFT (twiddles-in-VGPR, E broadcast) ----------------
// out[b,n1,n2,n3] = (1/N) * sum_k1 (E.x*P + E.y*Qm),  (P,Qm) = pqi[n1][k1]
// Thread tid owns n1 = tid. Twiddles live in 64 VGPRs for the whole kernel.
__global__ __launch_bounds__(256) void k_ifft_x(const float2* __restrict__ E,
                                                float* __restrict__ out,
                                                const float2* __restrict__ pqi) {
  __shared__ float2 sE[2048];  // [k1][n3] 16 KB
  int b = blockIdx.x >> 8, n2 = blockIdx.x & 255;
  int tid = threadIdx.x;
  {
    const float4* Eg = (const float4*)E;
    float4* sE4 = (float4*)sE;
#pragma unroll
    for (int e = 0; e < 4; e++) {
      int i = tid + e * 256;            // 1024 float4
      int k1 = i >> 5, col = i & 31;    // 32 float4 per k1 row
      sE4[i] = Eg[((long)(b * 32 + k1) * 256 + n2) * 32 + col];
    }
  }
  // per-lane twiddles: row n1 = tid of pqi, 32 complex (P,Qm) -> 64 VGPRs
  float2 tw[32];
  {
    const float4* pq4 = (const float4*)(pqi + tid * 32);
#pragma unroll
    for (int k = 0; k < 16; k++) {
      float4 v = pq4[k];
      tw[2 * k]     = make_float2(v.x, v.y);
      tw[2 * k + 1] = make_float2(v.z, v.w);
    }
  }
  __syncthreads();
  const float invN = 1.0f / (256.0f * 256.0f * 64.0f);
  float* ob = out + (long)b * 4194304 + (long)tid * 16384 + n2 * 64;
#pragma unroll 1
  for (int p = 0; p < 4; p++) {  // n3 in chunks of 16
    float acc[16];
#pragma unroll
    for (int j = 0; j < 16; j++) acc[j] = 0.f;
#pragma unroll
    for (int k1 = 0; k1 < 32; k1++) {
      const float2* er = &sE[k1 * 64 + p * 16];  // uniform addr -> broadcast
      float px = tw[k1].x, qy = tw[k1].y;
#pragma unroll
      for (int j = 0; j < 16; j++) {
        float2 ev = er[j];
        acc[j] = fmaf(ev.x, px, acc[j]);
        acc[j] = fmaf(ev.y, qy, acc[j]);
      }
    }
    float4* o4 = (float4*)(ob + p * 16);  // one full 64B line per lane per pass
#pragma unroll
    for (int j = 0; j < 4; j++)
      o4[j] = make_float4(acc[4 * j] * invN, acc[4 * j + 1] * invN,
                          acc[4 * j + 2] * invN, acc[4 * j + 3] * invN);
  }
}

extern "C" void kernel_launch(void* const* d_in, const int* in_sizes, int n_in,
                              void* d_out, int out_size, void* d_ws, size_t ws_size,
                              hipStream_t stream) {
  const float* x    = (const float*)d_in[0];
  const float* w_tl = (const float*)d_in[1];
  const float* w_tr = (const float*)d_in[2];
  const float* w_bl = (const float*)d_in[3];
  const float* w_br = (const float*)d_in[4];
  const float* b_tl = (const float*)d_in[5];
  const float* b_tr = (const float*)d_in[6];
  const float* b_bl = (const float*)d_in[7];
  const float* b_br = (const float*)d_in[8];
  float* out = (float*)d_out;
  char* ws = (char*)d_ws;

  // Workspace layout (bytes):
  float2* Bm  = (float2*)(ws + 0);          //  8,388,608  (8,256,32,16) c64
  float*  y   = (float*)(ws + 8388608);     //  2,097,152  (8,32,32,16)  f32
  float2* E   = (float2*)(ws + 10485760);   // 33,554,432  (8,32,256,64) c64
  float2* WT  = (float2*)(ws + 44040192);   //  8 KB
  float2* WXY = (float2*)(ws + 44048384);   // 64 KB
  float2* VT  = (float2*)(ws + 44113920);   //  8 KB
  float2* VXY = (float2*)(ws + 44122112);   // 64 KB
  float2* PQF = (float2*)(ws + 44187648);   // 64 KB
  float2* PQI = (float2*)(ws + 44253184);   // 64 KB  (end ~44.3 MB)
  // Stage-A output (67 MB) aliases d_out; dead before k_ifft_x writes out.
  float2* A = (float2*)d_out;

  k_tables<<<32, 256, 0, stream>>>(WT, WXY, VT, VXY, PQF, PQI);
  k_fft_t<<<8192, 256, 0, stream>>>(x, A, WT);
  k_fft_y<<<2048, 256, 0, stream>>>(A, Bm, WXY);
  k_fft_x<<<256, 512, 0, stream>>>(Bm, y, PQF, w_tl, w_tr, w_bl, w_br,
                                   b_tl, b_tr, b_bl, b_br);
  k_inv_te<<<2048, 256, 0, stream>>>(y, E, VT, VXY);
  k_ifft_x<<<2048, 256, 0, stream>>>(E, out, PQI);
}

// Round 4
// 215.349 us; speedup vs baseline: 2.5197x; 1.2832x over previous
//
#include <hip/hip_runtime.h>

#define PI_D 3.141592653589793238462643383279502884

// x (8,256,256,64) f32 -> out (8,256,256,64) f32.
// Forward padded FFT (272,272,80) pad=8; x_ft = Re(F)-Im(F) on 4 corner blocks.
// Inverse (256,256,64); out = Re(G)-Im(G).
// Re-Im collapse: Re-Im(sum a*w) = sum a.x*P + a.y*Qm, P=c-s, Qm=-(c+s).

// ---------------- twiddle tables (double-precision build) ----------------
__global__ void k_tables(float2* __restrict__ wt, float2* __restrict__ wxy,
                         float2* __restrict__ vt, float2* __restrict__ vxy,
                         float2* __restrict__ pqf, float2* __restrict__ pqi) {
  int t = blockIdx.x * blockDim.x + threadIdx.x;
  if (t < 64 * 16) {  // wt[n3][k3] = exp(-2pi i k3 (n3+8)/80)
    int n3 = t >> 4, k3 = t & 15;
    int ph = (k3 * (n3 + 8)) % 80;
    double a = -2.0 * PI_D * (double)ph / 80.0;
    wt[t] = make_float2((float)cos(a), (float)sin(a));
  }
  if (t < 256 * 32) {  // wxy[n][k] = exp(-2pi i kk (n+8)/272), kk = k<16 ? k : 240+k
    int n = t >> 5, k = t & 31;
    int kk = (k < 16) ? k : (240 + k);
    int ph = (kk * (n + 8)) % 272;
    double a = -2.0 * PI_D * (double)ph / 272.0;
    double c = cos(a), s = sin(a);
    wxy[t] = make_float2((float)c, (float)s);
    pqf[t] = make_float2((float)(c - s), (float)(-(c + s)));  // P, Qm (forward)
  }
  if (t < 16 * 64) {  // vt[k3][n3] = exp(+2pi i k3 n3 / 64)
    int k3 = t >> 6, n3 = t & 63;
    int ph = (k3 * n3) & 63;
    double a = 2.0 * PI_D * (double)ph / 64.0;
    vt[t] = make_float2((float)cos(a), (float)sin(a));
  }
  if (t < 256 * 32) {  // vxy[n][k] = exp(+2pi i k n / 256); pqi scaled by 1/N (exact pow2)
    int n = t >> 5, k = t & 31;
    int ph = (k * n) & 255;
    double a = 2.0 * PI_D * (double)ph / 256.0;
    double c = cos(a), s = sin(a);
    vxy[t] = make_float2((float)c, (float)s);
    const double inv = 1.0 / 4194304.0;  // 1/(256*256*64)
    pqi[t] = make_float2((float)((c - s) * inv), (float)((-(c + s)) * inv));
  }
}

// ---------------- Step A: T-axis forward DFT (LDS-transposed, coalesced) ----------------
// A[b,n1,n2,k3] = sum_n3 x[b,n1,n2,n3] * wt[n3][k3]
__global__ __launch_bounds__(256) void k_fft_t(const float* __restrict__ x,
                                               float2* __restrict__ A,
                                               const float2* __restrict__ wt) {
  __shared__ float sX[64][65];   // 64 rows x 64 cols, +1 pad
  __shared__ float2 swt[1024];   // wt[64][16]
  long blk = blockIdx.x;         // 8192 blocks x 64 rows
  int tid = threadIdx.x;
  const float4* xg = (const float4*)(x + blk * 4096);
#pragma unroll
  for (int e = 0; e < 4; e++) {
    int idx = tid + e * 256;  // 1024 float4, fully coalesced
    float4 v = xg[idx];
    int r = idx >> 4, c = (idx & 15) * 4;
    sX[r][c] = v.x; sX[r][c + 1] = v.y; sX[r][c + 2] = v.z; sX[r][c + 3] = v.w;
  }
#pragma unroll
  for (int e = 0; e < 4; e++) swt[tid + e * 256] = wt[tid + e * 256];
  __syncthreads();
  int r = tid >> 2, q = (tid & 3) * 4;  // row, k-quad
  float2 a0 = {0,0}, a1 = {0,0}, a2 = {0,0}, a3 = {0,0};
#pragma unroll 8
  for (int n3 = 0; n3 < 64; n3++) {
    float xv = sX[r][n3];
    const float2* wr = &swt[n3 * 16 + q];
    float2 w0 = wr[0], w1 = wr[1], w2 = wr[2], w3 = wr[3];
    a0.x = fmaf(xv, w0.x, a0.x); a0.y = fmaf(xv, w0.y, a0.y);
    a1.x = fmaf(xv, w1.x, a1.x); a1.y = fmaf(xv, w1.y, a1.y);
    a2.x = fmaf(xv, w2.x, a2.x); a2.y = fmaf(xv, w2.y, a2.y);
    a3.x = fmaf(xv, w3.x, a3.x); a3.y = fmaf(xv, w3.y, a3.y);
  }
  float4* Ao = (float4*)(A + (blk * 64 + r) * 16 + q);
  Ao[0] = make_float4(a0.x, a0.y, a1.x, a1.y);
  Ao[1] = make_float4(a2.x, a2.y, a3.x, a3.y);
}

// ---------------- Step B: Y-axis forward DFT (LDS-chunked twiddles) ----------------
// Bm[b,n1,k2,k3] = sum_n2 A[b,n1,n2,k3] * wxy[n2][k2]
__global__ __launch_bounds__(256) void k_fft_y(const float2* __restrict__ A,
                                               float2* __restrict__ Bm,
                                               const float2* __restrict__ wxy) {
  __shared__ float2 sA[4096];  // [n2][k3] 32 KB
  __shared__ float2 sW[2048];  // [64 n2][32 k2] chunk, 16 KB
  int bn1 = blockIdx.x;
  int tid = threadIdx.x;
  const float4* Ag = (const float4*)(A + (long)bn1 * 4096);
  float4* sA4 = (float4*)sA;
#pragma unroll
  for (int e = 0; e < 8; e++) sA4[tid + e * 256] = Ag[tid + e * 256];
  int k2 = tid >> 3, p = (tid & 7) * 2;  // two k3 per thread: p, p+1
  float2 r0 = {0,0}, r1 = {0,0};
  const float4* wg4 = (const float4*)wxy;
  float4* sW4 = (float4*)sW;
  for (int ch = 0; ch < 4; ch++) {
    __syncthreads();  // also covers the sA staging before ch 0
#pragma unroll
    for (int e = 0; e < 4; e++) sW4[tid + e * 256] = wg4[ch * 1024 + tid + e * 256];
    __syncthreads();
#pragma unroll 4
    for (int t = 0; t < 64; t++) {
      float4 av = *(const float4*)&sA[(ch * 64 + t) * 16 + p];
      float2 w = sW[t * 32 + k2];
      r0.x = fmaf(av.x, w.x, r0.x); r0.x = fmaf(-av.y, w.y, r0.x);
      r0.y = fmaf(av.x, w.y, r0.y); r0.y = fmaf(av.y, w.x, r0.y);
      r1.x = fmaf(av.z, w.x, r1.x); r1.x = fmaf(-av.w, w.y, r1.x);
      r1.y = fmaf(av.z, w.y, r1.y); r1.y = fmaf(av.w, w.x, r1.y);
    }
  }
  float4* Bo = (float4*)(Bm + (long)bn1 * 512 + k2 * 16 + p);
  *Bo = make_float4(r0.x, r0.y, r1.x, r1.y);
}

// ---------------- Step C: X-axis forward DFT (all-LDS, Re-Im collapsed) ----------------
__global__ __launch_bounds__(512) void k_fft_x(
    const float2* __restrict__ Bm, float* __restrict__ y,
    const float2* __restrict__ pqf,
    const float* __restrict__ w_tl, const float* __restrict__ w_tr,
    const float* __restrict__ w_bl, const float* __restrict__ w_br,
    const float* __restrict__ b_tl, const float* __restrict__ b_tr,
    const float* __restrict__ b_bl, const float* __restrict__ b_br) {
  __shared__ float2 sB[4096];   // [n1][k3] 32 KB
  __shared__ float2 sPQ[8192];  // full pqf table, 64 KB  (96 KB total, 1 block/CU)
  int b = blockIdx.x >> 5, k2 = blockIdx.x & 31;
  int tid = threadIdx.x;
  for (int i = tid; i < 4096; i += 512) {
    sB[i] = Bm[((long)(b * 256 + (i >> 4)) * 32 + k2) * 16 + (i & 15)];
  }
  const float4* pq4 = (const float4*)pqf;
  float4* sPQ4 = (float4*)sPQ;
#pragma unroll
  for (int e = 0; e < 8; e++) sPQ4[tid + e * 512] = pq4[tid + e * 512];
  __syncthreads();
  int k1 = tid >> 4, k3 = tid & 15;
  float acc = 0.f;
#pragma unroll 8
  for (int n1 = 0; n1 < 256; n1++) {
    float2 a = sB[n1 * 16 + k3];
    float2 w = sPQ[n1 * 32 + k1];  // (P, Qm)
    acc = fmaf(a.x, w.x, acc);
    acc = fmaf(a.y, w.y, acc);
  }
  const float* wsel = (k1 < 16) ? ((k2 < 16) ? w_tl : w_bl) : ((k2 < 16) ? w_tr : w_br);
  const float* bsel = (k1 < 16) ? ((k2 < 16) ? b_tl : b_bl) : ((k2 < 16) ? b_tr : b_br);
  int idx = ((k1 & 15) * 16 + (k2 & 15)) * 16 + k3;
  y[((b * 32 + k1) * 32 + k2) * 16 + k3] = fmaf(acc, wsel[idx], bsel[idx]);
}

// ---------------- Steps D+E fused: T-axis then Y-axis inverse DFT ----------------
// D[k2,n3] = sum_k3 y[b,k1,k2,k3]*vt[k3][n3]  (recomputed per block in LDS)
// E[b,k1,n2,n3] = sum_k2 D[k2,n3] * vxy[n2][k2]
__global__ __launch_bounds__(256) void k_inv_te(const float* __restrict__ y,
                                                float2* __restrict__ E,
                                                const float2* __restrict__ vt,
                                                const float2* __restrict__ vxy) {
  __shared__ float sy[512];     // y[b,k1,:,:]  32x16
  __shared__ float2 svt[1024];  // vt[16][64]
  __shared__ float2 sD[2048];   // D[k2][n3]  32x64
  __shared__ float2 sV[1024];   // vxy rows c*32 .. c*32+31, 8 KB
  int blk = blockIdx.x;         // (b*32+k1)*8 + c
  int c = blk & 7, bk1 = blk >> 3;
  int tid = threadIdx.x;
  ((float2*)sy)[tid] = ((const float2*)(y + (long)bk1 * 512))[tid];
#pragma unroll
  for (int e = 0; e < 4; e++) svt[tid + e * 256] = vt[tid + e * 256];
#pragma unroll
  for (int e = 0; e < 4; e++) sV[tid + e * 256] = vxy[c * 1024 + tid + e * 256];
  __syncthreads();
#pragma unroll
  for (int e = 0; e < 8; e++) {
    int idx = tid + e * 256;
    int k2 = idx >> 6, n3i = idx & 63;
    float ax = 0.f, ay = 0.f;
#pragma unroll
    for (int k3 = 0; k3 < 16; k3++) {
      float yv = sy[k2 * 16 + k3];
      float2 v = svt[k3 * 64 + n3i];
      ax = fmaf(yv, v.x, ax); ay = fmaf(yv, v.y, ay);
    }
    sD[idx] = make_float2(ax, ay);
  }
  __syncthreads();
  int n3 = tid & 63, wv = tid >> 6;
  float dx[32], dy[32];
#pragma unroll
  for (int k2 = 0; k2 < 32; k2++) { float2 t = sD[k2 * 64 + n3]; dx[k2] = t.x; dy[k2] = t.y; }
  for (int i = 0; i < 8; i += 2) {
    int l2 = wv * 8 + i;               // local n2 row in sV
    const float2* va = &sV[l2 * 32];   // broadcast reads
    const float2* vb = va + 32;
    float arx = 0.f, ary = 0.f, brx = 0.f, bry = 0.f;
#pragma unroll 8
    for (int k2 = 0; k2 < 32; k2++) {
      float2 w = va[k2];
      arx = fmaf(dx[k2], w.x, arx); arx = fmaf(-dy[k2], w.y, arx);
      ary = fmaf(dx[k2], w.y, ary); ary = fmaf(dy[k2], w.x, ary);
      float2 u = vb[k2];
      brx = fmaf(dx[k2], u.x, brx); brx = fmaf(-dy[k2], u.y, brx);
      bry = fmaf(dx[k2], u.y, bry); bry = fmaf(dy[k2], u.x, bry);
    }
    int n2a = c * 32 + l2;
    E[((long)bk1 * 256 + n2a) * 64 + n3] = make_float2(arx, ary);
    E[((long)bk1 * 256 + n2a + 1) * 64 + n3] = make_float2(brx, bry);
  }
}

// ---------------- Step F: X-axis inverse DFT as register-blocked GEMM ----------------
// Per batch: out[256 n1, 16384 col] = W[256, 64] x D[64, 16384]
//   W[n1][2k1]=P*invN, W[n1][2k1+1]=Qm*invN;  D[2k1][col]=Ex, D[2k1+1][col]=Ey.
// Block: 64 n1 x 128 cols, K=64 fully in LDS. Thread: 4x8 accumulator.
__global__ __launch_bounds__(256) void k_ifft_x(const float2* __restrict__ E,
                                                float* __restrict__ out,
                                                const float2* __restrict__ pqi) {
  __shared__ float sW[64][64];   // [kk][n1 local] 16 KB
  __shared__ float sD[64][128];  // [kk][col local] 32 KB
  int blk = blockIdx.x;          // ((b*4 + t1)*128 + tc)
  int tc = blk & 127, t1 = (blk >> 7) & 3, b = blk >> 9;
  int tid = threadIdx.x;
  int n1base = t1 * 64;
  // stage W (16 KB from the L2-hot 64 KB pqi table; bank-conflict-free writes)
  {
    const float4* pq4 = (const float4*)(pqi + (long)n1base * 32);
#pragma unroll
    for (int e = 0; e < 4; e++) {
      int q = tid + e * 256;       // 1024 quads: row i (n1 local), quad r (k1 pair)
      int i = q & 63, r = q >> 6;  // r = 0..15
      float4 v = pq4[i * 16 + r];  // (P_{2r},Qm_{2r},P_{2r+1},Qm_{2r+1})
      sW[4 * r][i] = v.x; sW[4 * r + 1][i] = v.y;
      sW[4 * r + 2][i] = v.z; sW[4 * r + 3][i] = v.w;
    }
  }
  // stage D (32 KB of E, coalesced 32 B/lane reads, b128 LDS writes)
  {
    const float4* Eg = (const float4*)E;
    long base = (long)b * 262144 + tc * 64;  // b*32*8192
#pragma unroll
    for (int e = 0; e < 4; e++) {
      int tq = tid + e * 256;      // 1024 tasks: k1, col-quad
      int k1 = tq >> 5, cq = tq & 31;
      const float4* src = Eg + base + (long)k1 * 8192 + 2 * cq;
      float4 v0 = src[0], v1 = src[1];
      *(float4*)&sD[2 * k1][4 * cq]     = make_float4(v0.x, v0.z, v1.x, v1.z);
      *(float4*)&sD[2 * k1 + 1][4 * cq] = make_float4(v0.y, v0.w, v1.y, v1.w);
    }
  }
  __syncthreads();
  int tn = tid & 15, tm = tid >> 4;
  float acc[4][8];
#pragma unroll
  for (int mi = 0; mi < 4; mi++)
#pragma unroll
    for (int j = 0; j < 8; j++) acc[mi][j] = 0.f;
#pragma unroll 8
  for (int kk = 0; kk < 64; kk++) {
    float4 wv = *(const float4*)&sW[kk][tm * 4];       // 4 bcast groups, banks 0-15
    float4 d0 = *(const float4*)&sD[kk][tn * 4];       // 256 B contiguous
    float4 d1 = *(const float4*)&sD[kk][64 + tn * 4];  // 256 B contiguous
    float w0 = wv.x, w1 = wv.y, w2 = wv.z, w3 = wv.w;
    acc[0][0] = fmaf(w0, d0.x, acc[0][0]); acc[0][1] = fmaf(w0, d0.y, acc[0][1]);
    acc[0][2] = fmaf(w0, d0.z, acc[0][2]); acc[0][3] = fmaf(w0, d0.w, acc[0][3]);
    acc[0][4] = fmaf(w0, d1.x, acc[0][4]); acc[0][5] = fmaf(w0, d1.y, acc[0][5]);
    acc[0][6] = fmaf(w0, d1.z, acc[0][6]); acc[0][7] = fmaf(w0, d1.w, acc[0][7]);
    acc[1][0] = fmaf(w1, d0.x, acc[1][0]); acc[1][1] = fmaf(w1, d0.y, acc[1][1]);
    acc[1][2] = fmaf(w1, d0.z, acc[1][2]); acc[1][3] = fmaf(w1, d0.w, acc[1][3]);
    acc[1][4] = fmaf(w1, d1.x, acc[1][4]); acc[1][5] = fmaf(w1, d1.y, acc[1][5]);
    acc[1][6] = fmaf(w1, d1.z, acc[1][6]); acc[1][7] = fmaf(w1, d1.w, acc[1][7]);
    acc[2][0] = fmaf(w2, d0.x, acc[2][0]); acc[2][1] = fmaf(w2, d0.y, acc[2][1]);
    acc[2][2] = fmaf(w2, d0.z, acc[2][2]); acc[2][3] = fmaf(w2, d0.w, acc[2][3]);
    acc[2][4] = fmaf(w2, d1.x, acc[2][4]); acc[2][5] = fmaf(w2, d1.y, acc[2][5]);
    acc[2][6] = fmaf(w2, d1.z, acc[2][6]); acc[2][7] = fmaf(w2, d1.w, acc[2][7]);
    acc[3][0] = fmaf(w3, d0.x, acc[3][0]); acc[3][1] = fmaf(w3, d0.y, acc[3][1]);
    acc[3][2] = fmaf(w3, d0.z, acc[3][2]); acc[3][3] = fmaf(w3, d0.w, acc[3][3]);
    acc[3][4] = fmaf(w3, d1.x, acc[3][4]); acc[3][5] = fmaf(w3, d1.y, acc[3][5]);
    acc[3][6] = fmaf(w3, d1.z, acc[3][6]); acc[3][7] = fmaf(w3, d1.w, acc[3][7]);
  }
  // write 4 rows x (2x16B); lanes tn=0..15 contiguous 256 B per row-group
  float* ob = out + (long)b * 4194304 + (long)(n1base + tm * 4) * 16384 + tc * 128;
#pragma unroll
  for (int mi = 0; mi < 4; mi++) {
    float4* o = (float4*)(ob + (long)mi * 16384);
    o[tn]      = make_float4(acc[mi][0], acc[mi][1], acc[mi][2], acc[mi][3]);
    o[16 + tn] = make_float4(acc[mi][4], acc[mi][5], acc[mi][6], acc[mi][7]);
  }
}

extern "C" void kernel_launch(void* const* d_in, const int* in_sizes, int n_in,
                              void* d_out, int out_size, void* d_ws, size_t ws_size,
                              hipStream_t stream) {
  const float* x    = (const float*)d_in[0];
  const float* w_tl = (const float*)d_in[1];
  const float* w_tr = (const float*)d_in[2];
  const float* w_bl = (const float*)d_in[3];
  const float* w_br = (const float*)d_in[4];
  const float* b_tl = (const float*)d_in[5];
  const float* b_tr = (const float*)d_in[6];
  const float* b_bl = (const float*)d_in[7];
  const float* b_br = (const float*)d_in[8];
  float* out = (float*)d_out;
  char* ws = (char*)d_ws;

  // Workspace layout (bytes):
  float2* Bm  = (float2*)(ws + 0);          //  8,388,608  (8,256,32,16) c64
  float*  y   = (float*)(ws + 8388608);     //  2,097,152  (8,32,32,16)  f32
  float2* E   = (float2*)(ws + 10485760);   // 33,554,432  (8,32,256,64) c64
  float2* WT  = (float2*)(ws + 44040192);   //  8 KB
  float2* WXY = (float2*)(ws + 44048384);   // 64 KB
  float2* VT  = (float2*)(ws + 44113920);   //  8 KB
  float2* VXY = (float2*)(ws + 44122112);   // 64 KB
  float2* PQF = (float2*)(ws + 44187648);   // 64 KB
  float2* PQI = (float2*)(ws + 44253184);   // 64 KB  (end ~44.3 MB)
  // Stage-A output (67 MB) aliases d_out; dead before k_ifft_x writes out.
  float2* A = (float2*)d_out;

  k_tables<<<32, 256, 0, stream>>>(WT, WXY, VT, VXY, PQF, PQI);
  k_fft_t<<<8192, 256, 0, stream>>>(x, A, WT);
  k_fft_y<<<2048, 256, 0, stream>>>(A, Bm, WXY);
  k_fft_x<<<256, 512, 0, stream>>>(Bm, y, PQF, w_tl, w_tr, w_bl, w_br,
                                   b_tl, b_tr, b_bl, b_br);
  k_inv_te<<<2048, 256, 0, stream>>>(y, E, VT, VXY);
  k_ifft_x<<<4096, 256, 0, stream>>>(E, out, PQI);
}